// Round 7
// baseline (1258.250 us; speedup 1.0000x reference)
//
#include <hip/hip_runtime.h>

#define S_LEN 2048
#define NH 16
#define DH 64
#define DM 1024
#define NB 2
#define BS 4096  // NB*S_LEN

typedef __attribute__((ext_vector_type(4))) float f32x4;
typedef __attribute__((ext_vector_type(8))) short bfrag;  // 8 bf16 in 4 VGPRs

__device__ __forceinline__ unsigned short f2bf(float f) {
    unsigned u = __builtin_bit_cast(unsigned, f);
    u += 0x7FFFu + ((u >> 16) & 1u);
    return (unsigned short)(u >> 16);
}

// barrier that waits only LDS ops (leaves global prefetch loads in flight)
__device__ __forceinline__ void bar_lgkm() {
    asm volatile("s_waitcnt lgkmcnt(0)" ::: "memory");
    __builtin_amdgcn_s_barrier();
}

// async global->LDS, 16B per lane; LDS dest must be wave-uniform base (+lane*16 implicit)
__device__ __forceinline__ void gld16(const unsigned short* g, unsigned short* l) {
    __builtin_amdgcn_global_load_lds((const __attribute__((address_space(1))) void*)g,
                                     (__attribute__((address_space(3))) void*)l, 16, 0, 0);
}

// ---------------- all 7 fp32 -> bf16 casts in one kernel ----------------
__global__ __launch_bounds__(256) void cast_all(const float* __restrict__ Q,
                                                const float* __restrict__ K,
                                                const float* __restrict__ V,
                                                const float* __restrict__ Wq,
                                                const float* __restrict__ Wk,
                                                const float* __restrict__ Wv,
                                                const float* __restrict__ Wo,
                                                unsigned short* __restrict__ Qc,
                                                unsigned short* __restrict__ Kc,
                                                unsigned short* __restrict__ Vc,
                                                unsigned short* __restrict__ Wqc,
                                                unsigned short* __restrict__ Wkc,
                                                unsigned short* __restrict__ Wvc,
                                                unsigned short* __restrict__ Woc) {
    int i = blockIdx.x * 256 + threadIdx.x;  // over 4,194,304 float4 chunks
    const float* src;
    unsigned short* dst;
    int off;
    if (i < 3145728) {                       // Q/K/V: 3 x 2^20 chunks
        int w = i >> 20;
        off = i & 1048575;
        src = (w == 0) ? Q : (w == 1) ? K : V;
        dst = (w == 0) ? Qc : (w == 1) ? Kc : Vc;
    } else {                                 // weights: 4 x 2^18 chunks
        int j = i - 3145728;
        int w = j >> 18;
        off = j & 262143;
        src = (w == 0) ? Wq : (w == 1) ? Wk : (w == 2) ? Wv : Wo;
        dst = (w == 0) ? Wqc : (w == 1) ? Wkc : (w == 2) ? Wvc : Woc;
    }
    float4 v = reinterpret_cast<const float4*>(src)[off];
    ushort4 o;
    o.x = f2bf(v.x); o.y = f2bf(v.y); o.z = f2bf(v.z); o.w = f2bf(v.w);
    reinterpret_cast<ushort4*>(dst)[off] = o;
}

// ================= combined QKV projection (m97 structure) =================
__global__ __launch_bounds__(256) void gemm_qkv(const unsigned short* __restrict__ Qc,
                                                const unsigned short* __restrict__ Kc,
                                                const unsigned short* __restrict__ Vc,
                                                const unsigned short* __restrict__ Wqc,
                                                const unsigned short* __restrict__ Wkc,
                                                const unsigned short* __restrict__ Wvc,
                                                unsigned short* __restrict__ qh,
                                                unsigned short* __restrict__ kh,
                                                unsigned short* __restrict__ vT) {
    const int z = blockIdx.z;
    const unsigned short* A = (z == 0) ? Qc : (z == 1) ? Kc : Vc;
    const unsigned short* B = (z == 0) ? Wqc : (z == 1) ? Wkc : Wvc;
    const int tid = threadIdx.x, lane = tid & 63;
    const int l15 = lane & 15, lhi = lane >> 4;
    const int w = tid >> 6, wr = w >> 1, wc = w & 1;
    const int m0 = blockIdx.y * 128, n0 = blockIdx.x * 128;
    const int K = DM;
    const int lr8 = lane >> 3;             // row-in-8-row-group
    const int csw = (lane & 7) ^ lr8;      // swizzled 16B-chunk index (8 chunks/row)

    __shared__ unsigned short sA[128 * 64];
    __shared__ unsigned short sB[128 * 64];

    f32x4 acc[4][4];
#pragma unroll
    for (int i = 0; i < 4; ++i)
#pragma unroll
        for (int j = 0; j < 4; ++j) acc[i][j] = (f32x4){0.f, 0.f, 0.f, 0.f};

    for (int t = 0; t < 16; ++t) {
        const int k0 = t * 64;
#pragma unroll
        for (int i = 0; i < 4; ++i) {
            int g = w * 4 + i;
            int row = g * 8 + lr8;
            gld16(A + (size_t)(m0 + row) * K + k0 + csw * 8, sA + g * 512);
            gld16(B + (size_t)(n0 + row) * K + k0 + csw * 8, sB + g * 512);
        }
        __syncthreads();
#pragma unroll
        for (int kk = 0; kk < 2; ++kk) {
            bfrag a[4], b[4];
#pragma unroll
            for (int f = 0; f < 4; ++f) {
                int ra = wr * 64 + f * 16 + l15;
                a[f] = *reinterpret_cast<const bfrag*>(
                    sA + ra * 64 + (((kk * 4 + lhi) ^ (ra & 7)) << 3));
                int rb = wc * 64 + f * 16 + l15;
                b[f] = *reinterpret_cast<const bfrag*>(
                    sB + rb * 64 + (((kk * 4 + lhi) ^ (rb & 7)) << 3));
            }
#pragma unroll
            for (int fm = 0; fm < 4; ++fm)
#pragma unroll
                for (int fn = 0; fn < 4; ++fn)
                    acc[fm][fn] =
                        __builtin_amdgcn_mfma_f32_16x16x32_bf16(a[fm], b[fn], acc[fm][fn], 0, 0, 0);
        }
        __syncthreads();
    }

    if (z == 2) {
#pragma unroll
        for (int fm = 0; fm < 4; ++fm)
#pragma unroll
            for (int fn = 0; fn < 4; ++fn) {
                int sbase = m0 + wr * 64 + fm * 16 + (lhi << 2);
                int gcol = n0 + wc * 64 + fn * 16 + l15;
                int b = sbase >> 11, s = sbase & 2047, h = gcol >> 6, d = gcol & 63;
                ushort4 o;
                o.x = f2bf(acc[fm][fn][0]); o.y = f2bf(acc[fm][fn][1]);
                o.z = f2bf(acc[fm][fn][2]); o.w = f2bf(acc[fm][fn][3]);
                *reinterpret_cast<ushort4*>(vT + ((size_t)(b * NH + h) * DH + d) * S_LEN + s) = o;
            }
    } else {
        unsigned short* Out = (z == 0) ? qh : kh;
#pragma unroll
        for (int fm = 0; fm < 4; ++fm)
#pragma unroll
            for (int fn = 0; fn < 4; ++fn)
#pragma unroll
                for (int r = 0; r < 4; ++r) {
                    int grow = m0 + wr * 64 + fm * 16 + (lhi << 2) + r;
                    int gcol = n0 + wc * 64 + fn * 16 + l15;
                    int b = grow >> 11, s = grow & 2047, h = gcol >> 6, d = gcol & 63;
                    Out[((size_t)(b * NH + h) * S_LEN + s) * DH + d] = f2bf(acc[fm][fn][r]);
                }
    }
}

// ================= output projection =================
__global__ __launch_bounds__(256) void gemm_out(const unsigned short* __restrict__ A,
                                                const unsigned short* __restrict__ B,
                                                float* __restrict__ Out) {
    const int tid = threadIdx.x, lane = tid & 63;
    const int l15 = lane & 15, lhi = lane >> 4;
    const int w = tid >> 6, wr = w >> 1, wc = w & 1;
    const int m0 = blockIdx.y * 128, n0 = blockIdx.x * 128;
    const int K = DM, N = DM;
    const int lr8 = lane >> 3;
    const int csw = (lane & 7) ^ lr8;

    __shared__ unsigned short sA[128 * 64];
    __shared__ unsigned short sB[128 * 64];

    f32x4 acc[4][4];
#pragma unroll
    for (int i = 0; i < 4; ++i)
#pragma unroll
        for (int j = 0; j < 4; ++j) acc[i][j] = (f32x4){0.f, 0.f, 0.f, 0.f};

    for (int t = 0; t < 16; ++t) {
        const int k0 = t * 64;
#pragma unroll
        for (int i = 0; i < 4; ++i) {
            int g = w * 4 + i;
            int row = g * 8 + lr8;
            gld16(A + (size_t)(m0 + row) * K + k0 + csw * 8, sA + g * 512);
            gld16(B + (size_t)(n0 + row) * K + k0 + csw * 8, sB + g * 512);
        }
        __syncthreads();
#pragma unroll
        for (int kk = 0; kk < 2; ++kk) {
            bfrag a[4], b[4];
#pragma unroll
            for (int f = 0; f < 4; ++f) {
                int ra = wr * 64 + f * 16 + l15;
                a[f] = *reinterpret_cast<const bfrag*>(
                    sA + ra * 64 + (((kk * 4 + lhi) ^ (ra & 7)) << 3));
                int rb = wc * 64 + f * 16 + l15;
                b[f] = *reinterpret_cast<const bfrag*>(
                    sB + rb * 64 + (((kk * 4 + lhi) ^ (rb & 7)) << 3));
            }
#pragma unroll
            for (int fm = 0; fm < 4; ++fm)
#pragma unroll
                for (int fn = 0; fn < 4; ++fn)
                    acc[fm][fn] =
                        __builtin_amdgcn_mfma_f32_16x16x32_bf16(a[fm], b[fn], acc[fm][fn], 0, 0, 0);
        }
        __syncthreads();
    }

#pragma unroll
    for (int fm = 0; fm < 4; ++fm)
#pragma unroll
        for (int fn = 0; fn < 4; ++fn)
#pragma unroll
            for (int r = 0; r < 4; ++r) {
                int grow = m0 + wr * 64 + fm * 16 + (lhi << 2) + r;
                int gcol = n0 + wc * 64 + fn * 16 + l15;
                Out[(size_t)grow * N + gcol] = acc[fm][fn][r];
            }
}

// ================= fused scores + softmax + PV (swapped-operand) =================
// Phase 1 now: K double-buffered in LDS -> ONE barrier per tile.
// LDS: sQ 8K + sK dbuf 2x16K = 40 KB (phase 2 reuses first 32 KB) -> 4 blocks/CU.
__global__ __launch_bounds__(256, 4) void attn_fused(const unsigned short* __restrict__ qh,
                                                     const unsigned short* __restrict__ kh,
                                                     const unsigned short* __restrict__ vT,
                                                     const float* __restrict__ prev,
                                                     float* __restrict__ scores,
                                                     float* __restrict__ attn,
                                                     unsigned short* __restrict__ ctx) {
    const int z = blockIdx.z;         // b*NH + h
    const int m0 = blockIdx.x * 64;   // Q strip base
    const int tid = threadIdx.x;
    const int lane = tid & 63;
    const int w = tid >> 6;
    const int l15 = lane & 15, lhi = lane >> 4;

    __shared__ unsigned short smem[20480];     // 40 KB
    unsigned short* sQ = smem;                 // [64][64]   phase 1
    // sK double buffer: smem+4096 + (kt&1)*8192, each [128][64]
    unsigned short* sV = smem;                 // [64][128]  phase 2
    unsigned short* sP = smem + 8192;          // [64][128]  phase 2

    const unsigned short* Qz = qh + (size_t)z * S_LEN * DH;
    const unsigned short* Kz = kh + (size_t)z * S_LEN * DH;
    const unsigned short* Vz = vT + (size_t)z * DH * S_LEN;
    const size_t zbase = (size_t)z * S_LEN * S_LEN;
    const float scale = 0.125f;  // 1/sqrt(64)

    const int qrow = w * 16 + l15;                    // local q row this lane owns
    const float* prevRow = prev + zbase + (size_t)(m0 + qrow) * S_LEN;
    float* scoresRow = scores + zbase + (size_t)(m0 + qrow) * S_LEN;
    float* attnRow = attn + zbase + (size_t)(m0 + qrow) * S_LEN;
    const int c4 = lhi * 4;                           // col offset within 16-group

    // stage Q strip (visible at first bar_lgkm)
#pragma unroll
    for (int i = 0; i < 2; ++i) {
        int c = i * 256 + tid, row = c >> 3, col8 = c & 7;
        *reinterpret_cast<int4*>(sQ + row * 64 + ((col8 * 8) ^ ((row & 7) * 8))) =
            *reinterpret_cast<const int4*>(Qz + (size_t)(m0 + row) * DH + col8 * 8);
    }

    float m_r = -1e30f, l_r = 0.f;

    // prologue: tile-0 K + prev
    int4 kreg[4];
#pragma unroll
    for (int i = 0; i < 4; ++i) {
        int c = i * 256 + tid, row = c >> 3, col8 = c & 7;
        kreg[i] = *reinterpret_cast<const int4*>(Kz + (size_t)row * DH + col8 * 8);
    }
    f32x4 pv4[8];
#pragma unroll
    for (int fn = 0; fn < 8; ++fn)
        pv4[fn] = __builtin_nontemporal_load(
            reinterpret_cast<const f32x4*>(prevRow + fn * 16 + c4));

    // ---------- phase 1: ONE barrier per tile (K dbuf) ----------
    for (int kt = 0; kt < S_LEN / 128; ++kt) {
        const int n0 = kt * 128;
        unsigned short* pK = smem + 4096 + (kt & 1) * 8192;
#pragma unroll
        for (int i = 0; i < 4; ++i) {
            int c = i * 256 + tid, row = c >> 3, col8 = c & 7;
            *reinterpret_cast<int4*>(pK + row * 64 + ((col8 * 8) ^ ((row & 7) * 8))) = kreg[i];
        }
        if (kt < 15) {
            const int n1 = n0 + 128;
#pragma unroll
            for (int i = 0; i < 4; ++i) {
                int c = i * 256 + tid, row = c >> 3, col8 = c & 7;
                kreg[i] = *reinterpret_cast<const int4*>(Kz + (size_t)(n1 + row) * DH + col8 * 8);
            }
        }
        bar_lgkm();  // pK(t) visible; dbuf makes single barrier safe

        f32x4 acc[8];
#pragma unroll
        for (int fn = 0; fn < 8; ++fn) acc[fn] = (f32x4){0.f, 0.f, 0.f, 0.f};
#pragma unroll
        for (int kk = 0; kk < 2; ++kk) {
            bfrag qf = *reinterpret_cast<const bfrag*>(
                sQ + qrow * 64 + (((kk * 4 + lhi) ^ (qrow & 7)) << 3));
            bfrag kf[8];
#pragma unroll
            for (int f = 0; f < 8; ++f) {
                int rb = f * 16 + l15;
                kf[f] = *reinterpret_cast<const bfrag*>(
                    pK + rb * 64 + (((kk * 4 + lhi) ^ (rb & 7)) << 3));
            }
#pragma unroll
            for (int fn = 0; fn < 8; ++fn)
                acc[fn] = __builtin_amdgcn_mfma_f32_16x16x32_bf16(kf[fn], qf, acc[fn], 0, 0, 0);
        }

        // consume prev -> s; refill prev(t+1); store scores (float4)
#pragma unroll
        for (int fn = 0; fn < 8; ++fn)
#pragma unroll
            for (int r = 0; r < 4; ++r) acc[fn][r] = acc[fn][r] * scale + pv4[fn][r];
        if (kt < 15) {
            const int n1 = n0 + 128;
#pragma unroll
            for (int fn = 0; fn < 8; ++fn)
                pv4[fn] = __builtin_nontemporal_load(
                    reinterpret_cast<const f32x4*>(prevRow + n1 + fn * 16 + c4));
        }
#pragma unroll
        for (int fn = 0; fn < 8; ++fn)
            *reinterpret_cast<f32x4*>(scoresRow + n0 + fn * 16 + c4) = acc[fn];

        // online softmax (row owned by 4 lanes: this, ^16, ^32)
        float pm = acc[0][0];
#pragma unroll
        for (int fn = 0; fn < 8; ++fn)
#pragma unroll
            for (int r = 0; r < 4; ++r) pm = fmaxf(pm, acc[fn][r]);
        pm = fmaxf(pm, __shfl_xor(pm, 16));
        pm = fmaxf(pm, __shfl_xor(pm, 32));
        float mnew = fmaxf(m_r, pm);
        float psum = 0.f;
#pragma unroll
        for (int fn = 0; fn < 8; ++fn)
#pragma unroll
            for (int r = 0; r < 4; ++r) psum += __expf(acc[fn][r] - mnew);
        psum += __shfl_xor(psum, 16);
        psum += __shfl_xor(psum, 32);
        l_r = l_r * __expf(m_r - mnew) + psum;
        m_r = mnew;
    }

    const float inv_l = 1.0f / l_r;

    // ---------- phase 2 (reverse tile order: hottest scores first) ----------
    f32x4 acco[4];
#pragma unroll
    for (int fn = 0; fn < 4; ++fn) acco[fn] = (f32x4){0.f, 0.f, 0.f, 0.f};

    int4 vreg[4];
#pragma unroll
    for (int i = 0; i < 4; ++i) {
        int c = i * 256 + tid, row = c >> 4, col8 = c & 15;
        vreg[i] = *reinterpret_cast<const int4*>(Vz + (size_t)row * S_LEN + 15 * 128 + col8 * 8);
    }
    f32x4 sv4[8];
#pragma unroll
    for (int fn = 0; fn < 8; ++fn)
        sv4[fn] = __builtin_nontemporal_load(
            reinterpret_cast<const f32x4*>(scoresRow + 15 * 128 + fn * 16 + c4));

    for (int kt = 15; kt >= 0; --kt) {
        const int n0 = kt * 128;
        bar_lgkm();  // all waves done with prior sV/sP (and phase-1 sQ/sK reads first iter)
#pragma unroll
        for (int i = 0; i < 4; ++i) {
            int c = i * 256 + tid, row = c >> 4, col8 = c & 15;
            *reinterpret_cast<int4*>(sV + row * 128 + ((col8 ^ (row & 7)) << 3)) = vreg[i];
        }
        if (kt > 0) {
            const int n1 = n0 - 128;
#pragma unroll
            for (int i = 0; i < 4; ++i) {
                int c = i * 256 + tid, row = c >> 4, col8 = c & 15;
                vreg[i] = *reinterpret_cast<const int4*>(Vz + (size_t)row * S_LEN + n1 + col8 * 8);
            }
        }
        // p = exp(s-m)/l: write attn (NT float4), stage p into sP
#pragma unroll
        for (int fn = 0; fn < 8; ++fn) {
            f32x4 p4;
#pragma unroll
            for (int r = 0; r < 4; ++r) p4[r] = __expf(sv4[fn][r] - m_r) * inv_l;
            __builtin_nontemporal_store(p4,
                                        reinterpret_cast<f32x4*>(attnRow + n0 + fn * 16 + c4));
            ushort4 pb;
            pb.x = f2bf(p4[0]); pb.y = f2bf(p4[1]); pb.z = f2bf(p4[2]); pb.w = f2bf(p4[3]);
            int cch = (fn * 2 + (lhi >> 1)) ^ (qrow & 7);
            *reinterpret_cast<ushort4*>(sP + qrow * 128 + cch * 8 + (lhi & 1) * 4) = pb;
        }
        if (kt > 0) {
            const int n1 = n0 - 128;
#pragma unroll
            for (int fn = 0; fn < 8; ++fn)
                sv4[fn] = __builtin_nontemporal_load(
                    reinterpret_cast<const f32x4*>(scoresRow + n1 + fn * 16 + c4));
        }
        bar_lgkm();  // sV/sP visible
        // O^T += V^T @ P^T
#pragma unroll
        for (int kk = 0; kk < 4; ++kk) {
            bfrag pf = *reinterpret_cast<const bfrag*>(
                sP + qrow * 128 + (((kk * 4 + lhi) ^ (qrow & 7)) << 3));
            bfrag vf[4];
#pragma unroll
            for (int f = 0; f < 4; ++f) {
                int rv = f * 16 + l15;
                vf[f] = *reinterpret_cast<const bfrag*>(
                    sV + rv * 128 + (((kk * 4 + lhi) ^ (rv & 7)) << 3));
            }
#pragma unroll
            for (int fn = 0; fn < 4; ++fn)
                acco[fn] = __builtin_amdgcn_mfma_f32_16x16x32_bf16(vf[fn], pf, acco[fn], 0, 0, 0);
        }
    }

    // write ctx (b, s, h*DH + d) bf16; lane owns q-row, 4 consecutive d per fn
    const int b = z >> 4, h = z & 15;
    const int s = m0 + qrow;
#pragma unroll
    for (int fn = 0; fn < 4; ++fn) {
        int d0 = fn * 16 + c4;
        ushort4 o;
        o.x = f2bf(acco[fn][0]); o.y = f2bf(acco[fn][1]);
        o.z = f2bf(acco[fn][2]); o.w = f2bf(acco[fn][3]);
        *reinterpret_cast<ushort4*>(ctx + ((size_t)(b * S_LEN + s)) * DM + h * DH + d0) = o;
    }
}

extern "C" void kernel_launch(void* const* d_in, const int* in_sizes, int n_in, void* d_out,
                              int out_size, void* d_ws, size_t ws_size, hipStream_t stream) {
    const float* Q = (const float*)d_in[0];
    const float* K = (const float*)d_in[1];
    const float* V = (const float*)d_in[2];
    const float* prev = (const float*)d_in[3];
    const float* Wq = (const float*)d_in[4];
    const float* Wk = (const float*)d_in[5];
    const float* Wv = (const float*)d_in[6];
    const float* Wo = (const float*)d_in[7];

    float* out = (float*)d_out;
    float* attn = out + (size_t)BS * DM;
    float* scores = attn + (size_t)NB * NH * S_LEN * S_LEN;

    unsigned short* ws = (unsigned short*)d_ws;
    unsigned short* Qc = ws;
    unsigned short* Kc = Qc + (size_t)BS * DM;
    unsigned short* Vc = Kc + (size_t)BS * DM;
    unsigned short* Wqc = Vc + (size_t)BS * DM;
    unsigned short* Wkc = Wqc + (size_t)DM * DM;
    unsigned short* Wvc = Wkc + (size_t)DM * DM;
    unsigned short* Woc = Wvc + (size_t)DM * DM;
    unsigned short* qh = Woc + (size_t)DM * DM;    // (b,h,s,d) bf16
    unsigned short* kh = qh + (size_t)BS * DM;     // (b,h,s,d) bf16
    unsigned short* vT = kh + (size_t)BS * DM;     // (b,h,d,s) bf16
    unsigned short* ctx = vT + (size_t)BS * DM;    // (b,s,h*d) bf16

    // all casts in one launch (4,194,304 float4 chunks)
    cast_all<<<16384, 256, 0, stream>>>(Q, K, V, Wq, Wk, Wv, Wo,
                                        Qc, Kc, Vc, Wqc, Wkc, Wvc, Woc);

    // combined QKV projections (768 blocks)
    dim3 gq(DM / 128, BS / 128, 3);
    gemm_qkv<<<gq, 256, 0, stream>>>(Qc, Kc, Vc, Wqc, Wkc, Wvc, qh, kh, vT);

    // fused scores + softmax + PV (1024 blocks)
    // MEASUREMENT PROBE (this round only): launched TWICE for duplicate-launch
    // attribution -> attn_time ~= dur_round7 - 656 us. Remove next round.
    dim3 ga(S_LEN / 64, 1, NB * NH);
    attn_fused<<<ga, 256, 0, stream>>>(qh, kh, vT, prev, scores, attn, ctx);
    attn_fused<<<ga, 256, 0, stream>>>(qh, kh, vT, prev, scores, attn, ctx);

    // output projection (256 blocks)
    dim3 gp(DM / 128, BS / 128, 1);
    gemm_out<<<gp, 256, 0, stream>>>(ctx, Woc, out);
}

// Round 8
// 723.886 us; speedup vs baseline: 1.7382x; 1.7382x over previous
//
#include <hip/hip_runtime.h>

#define S_LEN 2048
#define NH 16
#define DH 64
#define DM 1024
#define NB 2
#define BS 4096  // NB*S_LEN

typedef __attribute__((ext_vector_type(4))) float f32x4;
typedef __attribute__((ext_vector_type(8))) short bfrag;  // 8 bf16 in 4 VGPRs

__device__ __forceinline__ unsigned short f2bf(float f) {
    unsigned u = __builtin_bit_cast(unsigned, f);
    u += 0x7FFFu + ((u >> 16) & 1u);
    return (unsigned short)(u >> 16);
}

// async global->LDS, 16B per lane; LDS dest must be wave-uniform base (+lane*16 implicit)
__device__ __forceinline__ void gld16(const unsigned short* g, unsigned short* l) {
    __builtin_amdgcn_global_load_lds((const __attribute__((address_space(1))) void*)g,
                                     (__attribute__((address_space(3))) void*)l, 16, 0, 0);
}

// ---------------- all 7 fp32 -> bf16 casts in one kernel ----------------
__global__ __launch_bounds__(256) void cast_all(const float* __restrict__ Q,
                                                const float* __restrict__ K,
                                                const float* __restrict__ V,
                                                const float* __restrict__ Wq,
                                                const float* __restrict__ Wk,
                                                const float* __restrict__ Wv,
                                                const float* __restrict__ Wo,
                                                unsigned short* __restrict__ Qc,
                                                unsigned short* __restrict__ Kc,
                                                unsigned short* __restrict__ Vc,
                                                unsigned short* __restrict__ Wqc,
                                                unsigned short* __restrict__ Wkc,
                                                unsigned short* __restrict__ Wvc,
                                                unsigned short* __restrict__ Woc) {
    int i = blockIdx.x * 256 + threadIdx.x;  // over 4,194,304 float4 chunks
    const float* src;
    unsigned short* dst;
    int off;
    if (i < 3145728) {                       // Q/K/V: 3 x 2^20 chunks
        int w = i >> 20;
        off = i & 1048575;
        src = (w == 0) ? Q : (w == 1) ? K : V;
        dst = (w == 0) ? Qc : (w == 1) ? Kc : Vc;
    } else {                                 // weights: 4 x 2^18 chunks
        int j = i - 3145728;
        int w = j >> 18;
        off = j & 262143;
        src = (w == 0) ? Wq : (w == 1) ? Wk : (w == 2) ? Wv : Wo;
        dst = (w == 0) ? Wqc : (w == 1) ? Wkc : (w == 2) ? Wvc : Woc;
    }
    float4 v = reinterpret_cast<const float4*>(src)[off];
    ushort4 o;
    o.x = f2bf(v.x); o.y = f2bf(v.y); o.z = f2bf(v.z); o.w = f2bf(v.w);
    reinterpret_cast<ushort4*>(dst)[off] = o;
}

// ================= combined QKV projection (m97 structure) =================
__global__ __launch_bounds__(256) void gemm_qkv(const unsigned short* __restrict__ Qc,
                                                const unsigned short* __restrict__ Kc,
                                                const unsigned short* __restrict__ Vc,
                                                const unsigned short* __restrict__ Wqc,
                                                const unsigned short* __restrict__ Wkc,
                                                const unsigned short* __restrict__ Wvc,
                                                unsigned short* __restrict__ qh,
                                                unsigned short* __restrict__ kh,
                                                unsigned short* __restrict__ vT) {
    const int z = blockIdx.z;
    const unsigned short* A = (z == 0) ? Qc : (z == 1) ? Kc : Vc;
    const unsigned short* B = (z == 0) ? Wqc : (z == 1) ? Wkc : Wvc;
    const int tid = threadIdx.x, lane = tid & 63;
    const int l15 = lane & 15, lhi = lane >> 4;
    const int w = tid >> 6, wr = w >> 1, wc = w & 1;
    const int m0 = blockIdx.y * 128, n0 = blockIdx.x * 128;
    const int K = DM;
    const int lr8 = lane >> 3;             // row-in-8-row-group
    const int csw = (lane & 7) ^ lr8;      // swizzled 16B-chunk index (8 chunks/row)

    __shared__ unsigned short sA[128 * 64];
    __shared__ unsigned short sB[128 * 64];

    f32x4 acc[4][4];
#pragma unroll
    for (int i = 0; i < 4; ++i)
#pragma unroll
        for (int j = 0; j < 4; ++j) acc[i][j] = (f32x4){0.f, 0.f, 0.f, 0.f};

    for (int t = 0; t < 16; ++t) {
        const int k0 = t * 64;
#pragma unroll
        for (int i = 0; i < 4; ++i) {
            int g = w * 4 + i;
            int row = g * 8 + lr8;
            gld16(A + (size_t)(m0 + row) * K + k0 + csw * 8, sA + g * 512);
            gld16(B + (size_t)(n0 + row) * K + k0 + csw * 8, sB + g * 512);
        }
        __syncthreads();
#pragma unroll
        for (int kk = 0; kk < 2; ++kk) {
            bfrag a[4], b[4];
#pragma unroll
            for (int f = 0; f < 4; ++f) {
                int ra = wr * 64 + f * 16 + l15;
                a[f] = *reinterpret_cast<const bfrag*>(
                    sA + ra * 64 + (((kk * 4 + lhi) ^ (ra & 7)) << 3));
                int rb = wc * 64 + f * 16 + l15;
                b[f] = *reinterpret_cast<const bfrag*>(
                    sB + rb * 64 + (((kk * 4 + lhi) ^ (rb & 7)) << 3));
            }
#pragma unroll
            for (int fm = 0; fm < 4; ++fm)
#pragma unroll
                for (int fn = 0; fn < 4; ++fn)
                    acc[fm][fn] =
                        __builtin_amdgcn_mfma_f32_16x16x32_bf16(a[fm], b[fn], acc[fm][fn], 0, 0, 0);
        }
        __syncthreads();
    }

    if (z == 2) {
#pragma unroll
        for (int fm = 0; fm < 4; ++fm)
#pragma unroll
            for (int fn = 0; fn < 4; ++fn) {
                int sbase = m0 + wr * 64 + fm * 16 + (lhi << 2);
                int gcol = n0 + wc * 64 + fn * 16 + l15;
                int b = sbase >> 11, s = sbase & 2047, h = gcol >> 6, d = gcol & 63;
                ushort4 o;
                o.x = f2bf(acc[fm][fn][0]); o.y = f2bf(acc[fm][fn][1]);
                o.z = f2bf(acc[fm][fn][2]); o.w = f2bf(acc[fm][fn][3]);
                *reinterpret_cast<ushort4*>(vT + ((size_t)(b * NH + h) * DH + d) * S_LEN + s) = o;
            }
    } else {
        unsigned short* Out = (z == 0) ? qh : kh;
#pragma unroll
        for (int fm = 0; fm < 4; ++fm)
#pragma unroll
            for (int fn = 0; fn < 4; ++fn)
#pragma unroll
                for (int r = 0; r < 4; ++r) {
                    int grow = m0 + wr * 64 + fm * 16 + (lhi << 2) + r;
                    int gcol = n0 + wc * 64 + fn * 16 + l15;
                    int b = grow >> 11, s = grow & 2047, h = gcol >> 6, d = gcol & 63;
                    Out[((size_t)(b * NH + h) * S_LEN + s) * DH + d] = f2bf(acc[fm][fn][r]);
                }
    }
}

// ================= output projection =================
__global__ __launch_bounds__(256) void gemm_out(const unsigned short* __restrict__ A,
                                                const unsigned short* __restrict__ B,
                                                float* __restrict__ Out) {
    const int tid = threadIdx.x, lane = tid & 63;
    const int l15 = lane & 15, lhi = lane >> 4;
    const int w = tid >> 6, wr = w >> 1, wc = w & 1;
    const int m0 = blockIdx.y * 128, n0 = blockIdx.x * 128;
    const int K = DM, N = DM;
    const int lr8 = lane >> 3;
    const int csw = (lane & 7) ^ lr8;

    __shared__ unsigned short sA[128 * 64];
    __shared__ unsigned short sB[128 * 64];

    f32x4 acc[4][4];
#pragma unroll
    for (int i = 0; i < 4; ++i)
#pragma unroll
        for (int j = 0; j < 4; ++j) acc[i][j] = (f32x4){0.f, 0.f, 0.f, 0.f};

    for (int t = 0; t < 16; ++t) {
        const int k0 = t * 64;
#pragma unroll
        for (int i = 0; i < 4; ++i) {
            int g = w * 4 + i;
            int row = g * 8 + lr8;
            gld16(A + (size_t)(m0 + row) * K + k0 + csw * 8, sA + g * 512);
            gld16(B + (size_t)(n0 + row) * K + k0 + csw * 8, sB + g * 512);
        }
        __syncthreads();
#pragma unroll
        for (int kk = 0; kk < 2; ++kk) {
            bfrag a[4], b[4];
#pragma unroll
            for (int f = 0; f < 4; ++f) {
                int ra = wr * 64 + f * 16 + l15;
                a[f] = *reinterpret_cast<const bfrag*>(
                    sA + ra * 64 + (((kk * 4 + lhi) ^ (ra & 7)) << 3));
                int rb = wc * 64 + f * 16 + l15;
                b[f] = *reinterpret_cast<const bfrag*>(
                    sB + rb * 64 + (((kk * 4 + lhi) ^ (rb & 7)) << 3));
            }
#pragma unroll
            for (int fm = 0; fm < 4; ++fm)
#pragma unroll
                for (int fn = 0; fn < 4; ++fn)
                    acc[fm][fn] =
                        __builtin_amdgcn_mfma_f32_16x16x32_bf16(a[fm], b[fn], acc[fm][fn], 0, 0, 0);
        }
        __syncthreads();
    }

#pragma unroll
    for (int fm = 0; fm < 4; ++fm)
#pragma unroll
        for (int fn = 0; fn < 4; ++fn)
#pragma unroll
            for (int r = 0; r < 4; ++r) {
                int grow = m0 + wr * 64 + fm * 16 + (lhi << 2) + r;
                int gcol = n0 + wc * 64 + fn * 16 + l15;
                Out[(size_t)grow * N + gcol] = acc[fm][fn][r];
            }
}

// ================= fused scores + softmax + PV: ZERO LDS, ZERO barriers =================
// Block = one (b,h) head, 64-row Q strip; wave w owns q-rows w*16..w*16+15 (q = l15).
// All MFMA fragments load directly from global:
//   Q frag (hoisted): qh[qrow][kk*32+lhi*8]      K frag: kh[key][kk*32+lhi*8]  (L2)
//   V frag: vT[d][n0+kk*32+lhi*8]                (L2)
// Phase 2 re-reads scores in pf-order (cols kk*32+lhi*8+h*4) so P packs lane-locally.
// Waves free-run: latency hidden purely by TLP + depth-1 register prefetch.
__global__ __launch_bounds__(256, 5) void attn_fused(const unsigned short* __restrict__ qh,
                                                     const unsigned short* __restrict__ kh,
                                                     const unsigned short* __restrict__ vT,
                                                     const float* __restrict__ prev,
                                                     float* __restrict__ scores,
                                                     float* __restrict__ attn,
                                                     unsigned short* __restrict__ ctx) {
    const int z = blockIdx.z;         // b*NH + h
    const int m0 = blockIdx.x * 64;   // Q strip base
    const int tid = threadIdx.x;
    const int lane = tid & 63;
    const int w = tid >> 6;
    const int l15 = lane & 15, lhi = lane >> 4;

    const unsigned short* Qz = qh + (size_t)z * S_LEN * DH;
    const unsigned short* Kz = kh + (size_t)z * S_LEN * DH;
    const unsigned short* Vz = vT + (size_t)z * DH * S_LEN;
    const size_t zbase = (size_t)z * S_LEN * S_LEN;
    const float scale = 0.125f;  // 1/sqrt(64)

    const int qrow = w * 16 + l15;    // local q row this lane owns
    const float* prevRow = prev + zbase + (size_t)(m0 + qrow) * S_LEN;
    float* scoresRow = scores + zbase + (size_t)(m0 + qrow) * S_LEN;
    float* attnRow = attn + zbase + (size_t)(m0 + qrow) * S_LEN;
    const int c4 = lhi * 4;           // phase-1 col offset within 16-group
    const int c8 = lhi * 8;           // phase-2 pf-order col offset within 32-group

    // Q fragments: loaded ONCE (d = kk*32 + lhi*8 .. +8)
    bfrag qf[2];
#pragma unroll
    for (int kk = 0; kk < 2; ++kk)
        qf[kk] = *reinterpret_cast<const bfrag*>(Qz + (size_t)(m0 + qrow) * DH + kk * 32 +
                                                 lhi * 8);

    float m_r = -1e30f, l_r = 0.f;

    // prologue: prev tile 0
    f32x4 pv4[4];
#pragma unroll
    for (int f = 0; f < 4; ++f)
        pv4[f] = __builtin_nontemporal_load(
            reinterpret_cast<const f32x4*>(prevRow + f * 16 + c4));

    // ---------- phase 1: 32 x 64-col tiles, no barriers ----------
    for (int kt = 0; kt < 32; ++kt) {
        const int n0 = kt * 64;
        // K fragments direct from L2
        bfrag kf[2][4];
#pragma unroll
        for (int kk = 0; kk < 2; ++kk)
#pragma unroll
            for (int f = 0; f < 4; ++f)
                kf[kk][f] = *reinterpret_cast<const bfrag*>(
                    Kz + (size_t)(n0 + f * 16 + l15) * DH + kk * 32 + lhi * 8);

        f32x4 acc[4];
#pragma unroll
        for (int f = 0; f < 4; ++f) acc[f] = (f32x4){0.f, 0.f, 0.f, 0.f};
#pragma unroll
        for (int kk = 0; kk < 2; ++kk)
#pragma unroll
            for (int f = 0; f < 4; ++f)
                acc[f] = __builtin_amdgcn_mfma_f32_16x16x32_bf16(kf[kk][f], qf[kk], acc[f], 0, 0, 0);

        // consume prev; refill for next tile; write scores
#pragma unroll
        for (int f = 0; f < 4; ++f)
#pragma unroll
            for (int r = 0; r < 4; ++r) acc[f][r] = acc[f][r] * scale + pv4[f][r];
        if (kt < 31) {
            const int n1 = n0 + 64;
#pragma unroll
            for (int f = 0; f < 4; ++f)
                pv4[f] = __builtin_nontemporal_load(
                    reinterpret_cast<const f32x4*>(prevRow + n1 + f * 16 + c4));
        }
#pragma unroll
        for (int f = 0; f < 4; ++f)
            *reinterpret_cast<f32x4*>(scoresRow + n0 + f * 16 + c4) = acc[f];

        // online softmax (row q spread over lanes l15, l15^16, l15^32, l15^48)
        float pm = acc[0][0];
#pragma unroll
        for (int f = 0; f < 4; ++f)
#pragma unroll
            for (int r = 0; r < 4; ++r) pm = fmaxf(pm, acc[f][r]);
        pm = fmaxf(pm, __shfl_xor(pm, 16));
        pm = fmaxf(pm, __shfl_xor(pm, 32));
        float mnew = fmaxf(m_r, pm);
        float psum = 0.f;
#pragma unroll
        for (int f = 0; f < 4; ++f)
#pragma unroll
            for (int r = 0; r < 4; ++r) psum += __expf(acc[f][r] - mnew);
        psum += __shfl_xor(psum, 16);
        psum += __shfl_xor(psum, 32);
        l_r = l_r * __expf(m_r - mnew) + psum;
        m_r = mnew;
    }

    const float inv_l = 1.0f / l_r;

    // ---------- phase 2: reverse order, no LDS, no barriers ----------
    f32x4 acco[4];
#pragma unroll
    for (int f = 0; f < 4; ++f) acco[f] = (f32x4){0.f, 0.f, 0.f, 0.f};

    // prologue: scores tile 31 in pf-order (cols kk*32 + c8 + h*4)
    f32x4 sv[2][2];
#pragma unroll
    for (int kk = 0; kk < 2; ++kk)
#pragma unroll
        for (int h = 0; h < 2; ++h)
            sv[kk][h] = *reinterpret_cast<const f32x4*>(scoresRow + 31 * 64 + kk * 32 + c8 + h * 4);

    for (int kt = 31; kt >= 0; --kt) {
        const int n0 = kt * 64;
        // p = exp(s-m)/l; write attn; pack pf lane-locally (already in pf order)
        bfrag pf[2];
#pragma unroll
        for (int kk = 0; kk < 2; ++kk) {
#pragma unroll
            for (int h = 0; h < 2; ++h) {
                f32x4 p4;
#pragma unroll
                for (int r = 0; r < 4; ++r) p4[r] = __expf(sv[kk][h][r] - m_r) * inv_l;
                __builtin_nontemporal_store(
                    p4, reinterpret_cast<f32x4*>(attnRow + n0 + kk * 32 + c8 + h * 4));
#pragma unroll
                for (int r = 0; r < 4; ++r)
                    pf[kk][h * 4 + r] = (short)f2bf(p4[r]);
            }
        }
        // prefetch next tile's scores
        if (kt > 0) {
            const int n1 = n0 - 64;
#pragma unroll
            for (int kk = 0; kk < 2; ++kk)
#pragma unroll
                for (int h = 0; h < 2; ++h)
                    sv[kk][h] =
                        *reinterpret_cast<const f32x4*>(scoresRow + n1 + kk * 32 + c8 + h * 4);
        }
        // O^T += V^T @ P^T  (V frags direct from L2)
#pragma unroll
        for (int kk = 0; kk < 2; ++kk) {
            bfrag vf[4];
#pragma unroll
            for (int f = 0; f < 4; ++f)
                vf[f] = *reinterpret_cast<const bfrag*>(
                    Vz + (size_t)(f * 16 + l15) * S_LEN + n0 + kk * 32 + lhi * 8);
#pragma unroll
            for (int f = 0; f < 4; ++f)
                acco[f] = __builtin_amdgcn_mfma_f32_16x16x32_bf16(vf[f], pf[kk], acco[f], 0, 0, 0);
        }
    }

    // write ctx (b, s, h*DH + d) bf16; lane owns q-row, d = f*16 + lhi*4 + r
    const int b = z >> 4, h = z & 15;
    const int s = m0 + qrow;
#pragma unroll
    for (int f = 0; f < 4; ++f) {
        int d0 = f * 16 + c4;
        ushort4 o;
        o.x = f2bf(acco[f][0]); o.y = f2bf(acco[f][1]);
        o.z = f2bf(acco[f][2]); o.w = f2bf(acco[f][3]);
        *reinterpret_cast<ushort4*>(ctx + ((size_t)(b * S_LEN + s)) * DM + h * DH + d0) = o;
    }
}

extern "C" void kernel_launch(void* const* d_in, const int* in_sizes, int n_in, void* d_out,
                              int out_size, void* d_ws, size_t ws_size, hipStream_t stream) {
    const float* Q = (const float*)d_in[0];
    const float* K = (const float*)d_in[1];
    const float* V = (const float*)d_in[2];
    const float* prev = (const float*)d_in[3];
    const float* Wq = (const float*)d_in[4];
    const float* Wk = (const float*)d_in[5];
    const float* Wv = (const float*)d_in[6];
    const float* Wo = (const float*)d_in[7];

    float* out = (float*)d_out;
    float* attn = out + (size_t)BS * DM;
    float* scores = attn + (size_t)NB * NH * S_LEN * S_LEN;

    unsigned short* ws = (unsigned short*)d_ws;
    unsigned short* Qc = ws;
    unsigned short* Kc = Qc + (size_t)BS * DM;
    unsigned short* Vc = Kc + (size_t)BS * DM;
    unsigned short* Wqc = Vc + (size_t)BS * DM;
    unsigned short* Wkc = Wqc + (size_t)DM * DM;
    unsigned short* Wvc = Wkc + (size_t)DM * DM;
    unsigned short* Woc = Wvc + (size_t)DM * DM;
    unsigned short* qh = Woc + (size_t)DM * DM;    // (b,h,s,d) bf16
    unsigned short* kh = qh + (size_t)BS * DM;     // (b,h,s,d) bf16
    unsigned short* vT = kh + (size_t)BS * DM;     // (b,h,d,s) bf16
    unsigned short* ctx = vT + (size_t)BS * DM;    // (b,s,h*d) bf16

    // all casts in one launch
    cast_all<<<16384, 256, 0, stream>>>(Q, K, V, Wq, Wk, Wv, Wo,
                                        Qc, Kc, Vc, Wqc, Wkc, Wvc, Woc);

    // combined QKV projections (768 blocks)
    dim3 gq(DM / 128, BS / 128, 3);
    gemm_qkv<<<gq, 256, 0, stream>>>(Qc, Kc, Vc, Wqc, Wkc, Wvc, qh, kh, vT);

    // fused scores + softmax + PV (1024 blocks, LDS-free, barrier-free)
    dim3 ga(S_LEN / 64, 1, NB * NH);
    attn_fused<<<ga, 256, 0, stream>>>(qh, kh, vT, prev, scores, attn, ctx);

    // output projection (256 blocks)
    dim3 gp(DM / 128, BS / 128, 1);
    gemm_out<<<gp, 256, 0, stream>>>(ctx, Woc, out);
}

// Round 9
// 720.570 us; speedup vs baseline: 1.7462x; 1.0046x over previous
//
#include <hip/hip_runtime.h>

#define S_LEN 2048
#define NH 16
#define DH 64
#define DM 1024
#define NB 2
#define BS 4096  // NB*S_LEN

typedef __attribute__((ext_vector_type(4))) float f32x4;
typedef __attribute__((ext_vector_type(8))) short bfrag;  // 8 bf16 in 4 VGPRs

__device__ __forceinline__ unsigned short f2bf(float f) {
    unsigned u = __builtin_bit_cast(unsigned, f);
    u += 0x7FFFu + ((u >> 16) & 1u);
    return (unsigned short)(u >> 16);
}

// async global->LDS, 16B per lane; LDS dest must be wave-uniform base (+lane*16 implicit)
__device__ __forceinline__ void gld16(const unsigned short* g, unsigned short* l) {
    __builtin_amdgcn_global_load_lds((const __attribute__((address_space(1))) void*)g,
                                     (__attribute__((address_space(3))) void*)l, 16, 0, 0);
}

// ---------------- all 7 fp32 -> bf16 casts in one kernel ----------------
__global__ __launch_bounds__(256) void cast_all(const float* __restrict__ Q,
                                                const float* __restrict__ K,
                                                const float* __restrict__ V,
                                                const float* __restrict__ Wq,
                                                const float* __restrict__ Wk,
                                                const float* __restrict__ Wv,
                                                const float* __restrict__ Wo,
                                                unsigned short* __restrict__ Qc,
                                                unsigned short* __restrict__ Kc,
                                                unsigned short* __restrict__ Vc,
                                                unsigned short* __restrict__ Wqc,
                                                unsigned short* __restrict__ Wkc,
                                                unsigned short* __restrict__ Wvc,
                                                unsigned short* __restrict__ Woc) {
    int i = blockIdx.x * 256 + threadIdx.x;  // over 4,194,304 float4 chunks
    const float* src;
    unsigned short* dst;
    int off;
    if (i < 3145728) {                       // Q/K/V: 3 x 2^20 chunks
        int w = i >> 20;
        off = i & 1048575;
        src = (w == 0) ? Q : (w == 1) ? K : V;
        dst = (w == 0) ? Qc : (w == 1) ? Kc : Vc;
    } else {                                 // weights: 4 x 2^18 chunks
        int j = i - 3145728;
        int w = j >> 18;
        off = j & 262143;
        src = (w == 0) ? Wq : (w == 1) ? Wk : (w == 2) ? Wv : Wo;
        dst = (w == 0) ? Wqc : (w == 1) ? Wkc : (w == 2) ? Wvc : Woc;
    }
    float4 v = reinterpret_cast<const float4*>(src)[off];
    ushort4 o;
    o.x = f2bf(v.x); o.y = f2bf(v.y); o.z = f2bf(v.z); o.w = f2bf(v.w);
    reinterpret_cast<ushort4*>(dst)[off] = o;
}

// ================= combined QKV projection (m97 structure) =================
__global__ __launch_bounds__(256) void gemm_qkv(const unsigned short* __restrict__ Qc,
                                                const unsigned short* __restrict__ Kc,
                                                const unsigned short* __restrict__ Vc,
                                                const unsigned short* __restrict__ Wqc,
                                                const unsigned short* __restrict__ Wkc,
                                                const unsigned short* __restrict__ Wvc,
                                                unsigned short* __restrict__ qh,
                                                unsigned short* __restrict__ kh,
                                                unsigned short* __restrict__ vT) {
    const int z = blockIdx.z;
    const unsigned short* A = (z == 0) ? Qc : (z == 1) ? Kc : Vc;
    const unsigned short* B = (z == 0) ? Wqc : (z == 1) ? Wkc : Wvc;
    const int tid = threadIdx.x, lane = tid & 63;
    const int l15 = lane & 15, lhi = lane >> 4;
    const int w = tid >> 6, wr = w >> 1, wc = w & 1;
    const int m0 = blockIdx.y * 128, n0 = blockIdx.x * 128;
    const int K = DM;
    const int lr8 = lane >> 3;             // row-in-8-row-group
    const int csw = (lane & 7) ^ lr8;      // swizzled 16B-chunk index (8 chunks/row)

    __shared__ unsigned short sA[128 * 64];
    __shared__ unsigned short sB[128 * 64];

    f32x4 acc[4][4];
#pragma unroll
    for (int i = 0; i < 4; ++i)
#pragma unroll
        for (int j = 0; j < 4; ++j) acc[i][j] = (f32x4){0.f, 0.f, 0.f, 0.f};

    for (int t = 0; t < 16; ++t) {
        const int k0 = t * 64;
#pragma unroll
        for (int i = 0; i < 4; ++i) {
            int g = w * 4 + i;
            int row = g * 8 + lr8;
            gld16(A + (size_t)(m0 + row) * K + k0 + csw * 8, sA + g * 512);
            gld16(B + (size_t)(n0 + row) * K + k0 + csw * 8, sB + g * 512);
        }
        __syncthreads();
#pragma unroll
        for (int kk = 0; kk < 2; ++kk) {
            bfrag a[4], b[4];
#pragma unroll
            for (int f = 0; f < 4; ++f) {
                int ra = wr * 64 + f * 16 + l15;
                a[f] = *reinterpret_cast<const bfrag*>(
                    sA + ra * 64 + (((kk * 4 + lhi) ^ (ra & 7)) << 3));
                int rb = wc * 64 + f * 16 + l15;
                b[f] = *reinterpret_cast<const bfrag*>(
                    sB + rb * 64 + (((kk * 4 + lhi) ^ (rb & 7)) << 3));
            }
#pragma unroll
            for (int fm = 0; fm < 4; ++fm)
#pragma unroll
                for (int fn = 0; fn < 4; ++fn)
                    acc[fm][fn] =
                        __builtin_amdgcn_mfma_f32_16x16x32_bf16(a[fm], b[fn], acc[fm][fn], 0, 0, 0);
        }
        __syncthreads();
    }

    if (z == 2) {
#pragma unroll
        for (int fm = 0; fm < 4; ++fm)
#pragma unroll
            for (int fn = 0; fn < 4; ++fn) {
                int sbase = m0 + wr * 64 + fm * 16 + (lhi << 2);
                int gcol = n0 + wc * 64 + fn * 16 + l15;
                int b = sbase >> 11, s = sbase & 2047, h = gcol >> 6, d = gcol & 63;
                ushort4 o;
                o.x = f2bf(acc[fm][fn][0]); o.y = f2bf(acc[fm][fn][1]);
                o.z = f2bf(acc[fm][fn][2]); o.w = f2bf(acc[fm][fn][3]);
                *reinterpret_cast<ushort4*>(vT + ((size_t)(b * NH + h) * DH + d) * S_LEN + s) = o;
            }
    } else {
        unsigned short* Out = (z == 0) ? qh : kh;
#pragma unroll
        for (int fm = 0; fm < 4; ++fm)
#pragma unroll
            for (int fn = 0; fn < 4; ++fn)
#pragma unroll
                for (int r = 0; r < 4; ++r) {
                    int grow = m0 + wr * 64 + fm * 16 + (lhi << 2) + r;
                    int gcol = n0 + wc * 64 + fn * 16 + l15;
                    int b = grow >> 11, s = grow & 2047, h = gcol >> 6, d = gcol & 63;
                    Out[((size_t)(b * NH + h) * S_LEN + s) * DH + d] = f2bf(acc[fm][fn][r]);
                }
    }
}

// ================= output projection =================
__global__ __launch_bounds__(256) void gemm_out(const unsigned short* __restrict__ A,
                                                const unsigned short* __restrict__ B,
                                                float* __restrict__ Out) {
    const int tid = threadIdx.x, lane = tid & 63;
    const int l15 = lane & 15, lhi = lane >> 4;
    const int w = tid >> 6, wr = w >> 1, wc = w & 1;
    const int m0 = blockIdx.y * 128, n0 = blockIdx.x * 128;
    const int K = DM, N = DM;
    const int lr8 = lane >> 3;
    const int csw = (lane & 7) ^ lr8;

    __shared__ unsigned short sA[128 * 64];
    __shared__ unsigned short sB[128 * 64];

    f32x4 acc[4][4];
#pragma unroll
    for (int i = 0; i < 4; ++i)
#pragma unroll
        for (int j = 0; j < 4; ++j) acc[i][j] = (f32x4){0.f, 0.f, 0.f, 0.f};

    for (int t = 0; t < 16; ++t) {
        const int k0 = t * 64;
#pragma unroll
        for (int i = 0; i < 4; ++i) {
            int g = w * 4 + i;
            int row = g * 8 + lr8;
            gld16(A + (size_t)(m0 + row) * K + k0 + csw * 8, sA + g * 512);
            gld16(B + (size_t)(n0 + row) * K + k0 + csw * 8, sB + g * 512);
        }
        __syncthreads();
#pragma unroll
        for (int kk = 0; kk < 2; ++kk) {
            bfrag a[4], b[4];
#pragma unroll
            for (int f = 0; f < 4; ++f) {
                int ra = wr * 64 + f * 16 + l15;
                a[f] = *reinterpret_cast<const bfrag*>(
                    sA + ra * 64 + (((kk * 4 + lhi) ^ (ra & 7)) << 3));
                int rb = wc * 64 + f * 16 + l15;
                b[f] = *reinterpret_cast<const bfrag*>(
                    sB + rb * 64 + (((kk * 4 + lhi) ^ (rb & 7)) << 3));
            }
#pragma unroll
            for (int fm = 0; fm < 4; ++fm)
#pragma unroll
                for (int fn = 0; fn < 4; ++fn)
                    acc[fm][fn] =
                        __builtin_amdgcn_mfma_f32_16x16x32_bf16(a[fm], b[fn], acc[fm][fn], 0, 0, 0);
        }
        __syncthreads();
    }

#pragma unroll
    for (int fm = 0; fm < 4; ++fm)
#pragma unroll
        for (int fn = 0; fn < 4; ++fn)
#pragma unroll
            for (int r = 0; r < 4; ++r) {
                int grow = m0 + wr * 64 + fm * 16 + (lhi << 2) + r;
                int gcol = n0 + wc * 64 + fn * 16 + l15;
                Out[(size_t)grow * N + gcol] = acc[fm][fn][r];
            }
}

// ================= fused scores + softmax + PV: zero LDS, zero barriers,
// depth-1 register pipeline on ALL streams (K dbuf, prev reload, V early-issue,
// scores dbuf). Block = one (b,h), 64-row Q strip; wave w owns q-rows w*16+l15.
__global__ __launch_bounds__(256, 4) void attn_fused(const unsigned short* __restrict__ qh,
                                                     const unsigned short* __restrict__ kh,
                                                     const unsigned short* __restrict__ vT,
                                                     const float* __restrict__ prev,
                                                     float* __restrict__ scores,
                                                     float* __restrict__ attn,
                                                     unsigned short* __restrict__ ctx) {
    const int z = blockIdx.z;         // b*NH + h
    const int m0 = blockIdx.x * 64;   // Q strip base
    const int tid = threadIdx.x;
    const int lane = tid & 63;
    const int w = tid >> 6;
    const int l15 = lane & 15, lhi = lane >> 4;

    const unsigned short* Qz = qh + (size_t)z * S_LEN * DH;
    const unsigned short* Kz = kh + (size_t)z * S_LEN * DH;
    const unsigned short* Vz = vT + (size_t)z * DH * S_LEN;
    const size_t zbase = (size_t)z * S_LEN * S_LEN;
    const float scale = 0.125f;  // 1/sqrt(64)

    const int qrow = w * 16 + l15;
    const float* prevRow = prev + zbase + (size_t)(m0 + qrow) * S_LEN;
    float* scoresRow = scores + zbase + (size_t)(m0 + qrow) * S_LEN;
    float* attnRow = attn + zbase + (size_t)(m0 + qrow) * S_LEN;
    const int c4 = lhi * 4;
    const int c8 = lhi * 8;

    // Q fragments: loaded once
    bfrag qf[2];
#pragma unroll
    for (int kk = 0; kk < 2; ++kk)
        qf[kk] = *reinterpret_cast<const bfrag*>(Qz + (size_t)(m0 + qrow) * DH + kk * 32 +
                                                 lhi * 8);

    float m_r = -1e30f, l_r = 0.f;
    f32x4 pv4[4];

    auto loadK = [&](bfrag (&kf)[2][4], int kt) {
        const int n0 = kt * 64;
#pragma unroll
        for (int kk = 0; kk < 2; ++kk)
#pragma unroll
            for (int f = 0; f < 4; ++f)
                kf[kk][f] = *reinterpret_cast<const bfrag*>(
                    Kz + (size_t)(n0 + f * 16 + l15) * DH + kk * 32 + lhi * 8);
    };
    auto loadPrev = [&](int kt) {
        const int n0 = kt * 64;
#pragma unroll
        for (int f = 0; f < 4; ++f)
            pv4[f] = __builtin_nontemporal_load(
                reinterpret_cast<const f32x4*>(prevRow + n0 + f * 16 + c4));
    };
    // phase-1 body: MFMA(cur), issue K(kt+1)->nxt, consume prev, reload prev,
    // store scores, softmax (VALU chain covers the in-flight loads).
    auto p1body = [&](bfrag (&cur)[2][4], bfrag (&nxt)[2][4], int kt) {
        const int n0 = kt * 64;
        f32x4 acc[4];
#pragma unroll
        for (int f = 0; f < 4; ++f) acc[f] = (f32x4){0.f, 0.f, 0.f, 0.f};
#pragma unroll
        for (int kk = 0; kk < 2; ++kk)
#pragma unroll
            for (int f = 0; f < 4; ++f)
                acc[f] = __builtin_amdgcn_mfma_f32_16x16x32_bf16(cur[kk][f], qf[kk], acc[f], 0, 0, 0);
        if (kt < 31) loadK(nxt, kt + 1);
#pragma unroll
        for (int f = 0; f < 4; ++f)
#pragma unroll
            for (int r = 0; r < 4; ++r) acc[f][r] = acc[f][r] * scale + pv4[f][r];
        if (kt < 31) loadPrev(kt + 1);
#pragma unroll
        for (int f = 0; f < 4; ++f)
            *reinterpret_cast<f32x4*>(scoresRow + n0 + f * 16 + c4) = acc[f];
        float pm = acc[0][0];
#pragma unroll
        for (int f = 0; f < 4; ++f)
#pragma unroll
            for (int r = 0; r < 4; ++r) pm = fmaxf(pm, acc[f][r]);
        pm = fmaxf(pm, __shfl_xor(pm, 16));
        pm = fmaxf(pm, __shfl_xor(pm, 32));
        float mnew = fmaxf(m_r, pm);
        float psum = 0.f;
#pragma unroll
        for (int f = 0; f < 4; ++f)
#pragma unroll
            for (int r = 0; r < 4; ++r) psum += __expf(acc[f][r] - mnew);
        psum += __shfl_xor(psum, 16);
        psum += __shfl_xor(psum, 32);
        l_r = l_r * __expf(m_r - mnew) + psum;
        m_r = mnew;
    };

    {
        bfrag kfA[2][4], kfB[2][4];
        loadK(kfA, 0);
        loadPrev(0);
        for (int it = 0; it < 16; ++it) {
            p1body(kfA, kfB, it * 2);
            p1body(kfB, kfA, it * 2 + 1);
        }
    }

    const float inv_l = 1.0f / l_r;

    // ---------- phase 2: reverse order ----------
    f32x4 acco[4];
#pragma unroll
    for (int f = 0; f < 4; ++f) acco[f] = (f32x4){0.f, 0.f, 0.f, 0.f};

    auto loadS = [&](f32x4 (&sv)[2][2], int kt) {
        const int n0 = kt * 64;
#pragma unroll
        for (int kk = 0; kk < 2; ++kk)
#pragma unroll
            for (int h = 0; h < 2; ++h)
                sv[kk][h] =
                    *reinterpret_cast<const f32x4*>(scoresRow + n0 + kk * 32 + c8 + h * 4);
    };
    // phase-2 body: issue V(kt) + scores(kt-1) early; exp chain hides them; MFMA.
    auto p2body = [&](f32x4 (&cur)[2][2], f32x4 (&nxt)[2][2], int kt) {
        const int n0 = kt * 64;
        bfrag vf[2][4];
#pragma unroll
        for (int kk = 0; kk < 2; ++kk)
#pragma unroll
            for (int f = 0; f < 4; ++f)
                vf[kk][f] = *reinterpret_cast<const bfrag*>(
                    Vz + (size_t)(f * 16 + l15) * S_LEN + n0 + kk * 32 + lhi * 8);
        if (kt > 0) loadS(nxt, kt - 1);
        bfrag pf[2];
#pragma unroll
        for (int kk = 0; kk < 2; ++kk) {
#pragma unroll
            for (int h = 0; h < 2; ++h) {
                f32x4 p4;
#pragma unroll
                for (int r = 0; r < 4; ++r) p4[r] = __expf(cur[kk][h][r] - m_r) * inv_l;
                __builtin_nontemporal_store(
                    p4, reinterpret_cast<f32x4*>(attnRow + n0 + kk * 32 + c8 + h * 4));
#pragma unroll
                for (int r = 0; r < 4; ++r) pf[kk][h * 4 + r] = (short)f2bf(p4[r]);
            }
        }
#pragma unroll
        for (int kk = 0; kk < 2; ++kk)
#pragma unroll
            for (int f = 0; f < 4; ++f)
                acco[f] = __builtin_amdgcn_mfma_f32_16x16x32_bf16(vf[kk][f], pf[kk], acco[f], 0, 0, 0);
    };

    {
        f32x4 svA[2][2], svB[2][2];
        loadS(svA, 31);
        for (int it = 0; it < 16; ++it) {
            p2body(svA, svB, 31 - it * 2);
            p2body(svB, svA, 30 - it * 2);
        }
    }

    // write ctx (b, s, h*DH + d) bf16
    const int b = z >> 4, h = z & 15;
    const int s = m0 + qrow;
#pragma unroll
    for (int f = 0; f < 4; ++f) {
        int d0 = f * 16 + c4;
        ushort4 o;
        o.x = f2bf(acco[f][0]); o.y = f2bf(acco[f][1]);
        o.z = f2bf(acco[f][2]); o.w = f2bf(acco[f][3]);
        *reinterpret_cast<ushort4*>(ctx + ((size_t)(b * S_LEN + s)) * DM + h * DH + d0) = o;
    }
}

extern "C" void kernel_launch(void* const* d_in, const int* in_sizes, int n_in, void* d_out,
                              int out_size, void* d_ws, size_t ws_size, hipStream_t stream) {
    const float* Q = (const float*)d_in[0];
    const float* K = (const float*)d_in[1];
    const float* V = (const float*)d_in[2];
    const float* prev = (const float*)d_in[3];
    const float* Wq = (const float*)d_in[4];
    const float* Wk = (const float*)d_in[5];
    const float* Wv = (const float*)d_in[6];
    const float* Wo = (const float*)d_in[7];

    float* out = (float*)d_out;
    float* attn = out + (size_t)BS * DM;
    float* scores = attn + (size_t)NB * NH * S_LEN * S_LEN;

    unsigned short* ws = (unsigned short*)d_ws;
    unsigned short* Qc = ws;
    unsigned short* Kc = Qc + (size_t)BS * DM;
    unsigned short* Vc = Kc + (size_t)BS * DM;
    unsigned short* Wqc = Vc + (size_t)BS * DM;
    unsigned short* Wkc = Wqc + (size_t)DM * DM;
    unsigned short* Wvc = Wkc + (size_t)DM * DM;
    unsigned short* Woc = Wvc + (size_t)DM * DM;
    unsigned short* qh = Woc + (size_t)DM * DM;    // (b,h,s,d) bf16
    unsigned short* kh = qh + (size_t)BS * DM;     // (b,h,s,d) bf16
    unsigned short* vT = kh + (size_t)BS * DM;     // (b,h,d,s) bf16
    unsigned short* ctx = vT + (size_t)BS * DM;    // (b,s,h*d) bf16

    // all casts in one launch
    cast_all<<<16384, 256, 0, stream>>>(Q, K, V, Wq, Wk, Wv, Wo,
                                        Qc, Kc, Vc, Wqc, Wkc, Wvc, Woc);

    // combined QKV projections (768 blocks)
    dim3 gq(DM / 128, BS / 128, 3);
    gemm_qkv<<<gq, 256, 0, stream>>>(Qc, Kc, Vc, Wqc, Wkc, Wvc, qh, kh, vT);

    // fused scores + softmax + PV (1024 blocks, LDS-free, barrier-free, pipelined)
    dim3 ga(S_LEN / 64, 1, NB * NH);
    attn_fused<<<ga, 256, 0, stream>>>(qh, kh, vT, prev, scores, attn, ctx);

    // output projection (256 blocks)
    dim3 gp(DM / 128, BS / 128, 1);
    gemm_out<<<gp, 256, 0, stream>>>(ctx, Woc, out);
}

// Round 10
// 686.320 us; speedup vs baseline: 1.8333x; 1.0499x over previous
//
#include <hip/hip_runtime.h>

#define S_LEN 2048
#define NH 16
#define DH 64
#define DM 1024
#define NB 2
#define BS 4096  // NB*S_LEN

typedef __attribute__((ext_vector_type(4))) float f32x4;
typedef __attribute__((ext_vector_type(8))) short bfrag;  // 8 bf16 in 4 VGPRs

__device__ __forceinline__ unsigned short f2bf(float f) {
    unsigned u = __builtin_bit_cast(unsigned, f);
    u += 0x7FFFu + ((u >> 16) & 1u);
    return (unsigned short)(u >> 16);
}

// async global->LDS, 16B per lane; LDS dest must be wave-uniform base (+lane*16 implicit)
__device__ __forceinline__ void gld16(const unsigned short* g, unsigned short* l) {
    __builtin_amdgcn_global_load_lds((const __attribute__((address_space(1))) void*)g,
                                     (__attribute__((address_space(3))) void*)l, 16, 0, 0);
}

// ---------------- all 7 fp32 -> bf16 casts in one kernel ----------------
__global__ __launch_bounds__(256) void cast_all(const float* __restrict__ Q,
                                                const float* __restrict__ K,
                                                const float* __restrict__ V,
                                                const float* __restrict__ Wq,
                                                const float* __restrict__ Wk,
                                                const float* __restrict__ Wv,
                                                const float* __restrict__ Wo,
                                                unsigned short* __restrict__ Qc,
                                                unsigned short* __restrict__ Kc,
                                                unsigned short* __restrict__ Vc,
                                                unsigned short* __restrict__ Wqc,
                                                unsigned short* __restrict__ Wkc,
                                                unsigned short* __restrict__ Wvc,
                                                unsigned short* __restrict__ Woc) {
    int i = blockIdx.x * 256 + threadIdx.x;  // over 4,194,304 float4 chunks
    const float* src;
    unsigned short* dst;
    int off;
    if (i < 3145728) {                       // Q/K/V: 3 x 2^20 chunks
        int w = i >> 20;
        off = i & 1048575;
        src = (w == 0) ? Q : (w == 1) ? K : V;
        dst = (w == 0) ? Qc : (w == 1) ? Kc : Vc;
    } else {                                 // weights: 4 x 2^18 chunks
        int j = i - 3145728;
        int w = j >> 18;
        off = j & 262143;
        src = (w == 0) ? Wq : (w == 1) ? Wk : (w == 2) ? Wv : Wo;
        dst = (w == 0) ? Wqc : (w == 1) ? Wkc : (w == 2) ? Wvc : Woc;
    }
    float4 v = reinterpret_cast<const float4*>(src)[off];
    ushort4 o;
    o.x = f2bf(v.x); o.y = f2bf(v.y); o.z = f2bf(v.z); o.w = f2bf(v.w);
    reinterpret_cast<ushort4*>(dst)[off] = o;
}

// ================= combined QKV projection (m97 structure) =================
__global__ __launch_bounds__(256) void gemm_qkv(const unsigned short* __restrict__ Qc,
                                                const unsigned short* __restrict__ Kc,
                                                const unsigned short* __restrict__ Vc,
                                                const unsigned short* __restrict__ Wqc,
                                                const unsigned short* __restrict__ Wkc,
                                                const unsigned short* __restrict__ Wvc,
                                                unsigned short* __restrict__ qh,
                                                unsigned short* __restrict__ kh,
                                                unsigned short* __restrict__ vT) {
    const int z = blockIdx.z;
    const unsigned short* A = (z == 0) ? Qc : (z == 1) ? Kc : Vc;
    const unsigned short* B = (z == 0) ? Wqc : (z == 1) ? Wkc : Wvc;
    const int tid = threadIdx.x, lane = tid & 63;
    const int l15 = lane & 15, lhi = lane >> 4;
    const int w = tid >> 6, wr = w >> 1, wc = w & 1;
    const int m0 = blockIdx.y * 128, n0 = blockIdx.x * 128;
    const int K = DM;
    const int lr8 = lane >> 3;             // row-in-8-row-group
    const int csw = (lane & 7) ^ lr8;      // swizzled 16B-chunk index (8 chunks/row)

    __shared__ unsigned short sA[128 * 64];
    __shared__ unsigned short sB[128 * 64];

    f32x4 acc[4][4];
#pragma unroll
    for (int i = 0; i < 4; ++i)
#pragma unroll
        for (int j = 0; j < 4; ++j) acc[i][j] = (f32x4){0.f, 0.f, 0.f, 0.f};

    for (int t = 0; t < 16; ++t) {
        const int k0 = t * 64;
#pragma unroll
        for (int i = 0; i < 4; ++i) {
            int g = w * 4 + i;
            int row = g * 8 + lr8;
            gld16(A + (size_t)(m0 + row) * K + k0 + csw * 8, sA + g * 512);
            gld16(B + (size_t)(n0 + row) * K + k0 + csw * 8, sB + g * 512);
        }
        __syncthreads();
#pragma unroll
        for (int kk = 0; kk < 2; ++kk) {
            bfrag a[4], b[4];
#pragma unroll
            for (int f = 0; f < 4; ++f) {
                int ra = wr * 64 + f * 16 + l15;
                a[f] = *reinterpret_cast<const bfrag*>(
                    sA + ra * 64 + (((kk * 4 + lhi) ^ (ra & 7)) << 3));
                int rb = wc * 64 + f * 16 + l15;
                b[f] = *reinterpret_cast<const bfrag*>(
                    sB + rb * 64 + (((kk * 4 + lhi) ^ (rb & 7)) << 3));
            }
#pragma unroll
            for (int fm = 0; fm < 4; ++fm)
#pragma unroll
                for (int fn = 0; fn < 4; ++fn)
                    acc[fm][fn] =
                        __builtin_amdgcn_mfma_f32_16x16x32_bf16(a[fm], b[fn], acc[fm][fn], 0, 0, 0);
        }
        __syncthreads();
    }

    if (z == 2) {
#pragma unroll
        for (int fm = 0; fm < 4; ++fm)
#pragma unroll
            for (int fn = 0; fn < 4; ++fn) {
                int sbase = m0 + wr * 64 + fm * 16 + (lhi << 2);
                int gcol = n0 + wc * 64 + fn * 16 + l15;
                int b = sbase >> 11, s = sbase & 2047, h = gcol >> 6, d = gcol & 63;
                ushort4 o;
                o.x = f2bf(acc[fm][fn][0]); o.y = f2bf(acc[fm][fn][1]);
                o.z = f2bf(acc[fm][fn][2]); o.w = f2bf(acc[fm][fn][3]);
                *reinterpret_cast<ushort4*>(vT + ((size_t)(b * NH + h) * DH + d) * S_LEN + s) = o;
            }
    } else {
        unsigned short* Out = (z == 0) ? qh : kh;
#pragma unroll
        for (int fm = 0; fm < 4; ++fm)
#pragma unroll
            for (int fn = 0; fn < 4; ++fn)
#pragma unroll
                for (int r = 0; r < 4; ++r) {
                    int grow = m0 + wr * 64 + fm * 16 + (lhi << 2) + r;
                    int gcol = n0 + wc * 64 + fn * 16 + l15;
                    int b = grow >> 11, s = grow & 2047, h = gcol >> 6, d = gcol & 63;
                    Out[((size_t)(b * NH + h) * S_LEN + s) * DH + d] = f2bf(acc[fm][fn][r]);
                }
    }
}

// ================= output projection =================
__global__ __launch_bounds__(256) void gemm_out(const unsigned short* __restrict__ A,
                                                const unsigned short* __restrict__ B,
                                                float* __restrict__ Out) {
    const int tid = threadIdx.x, lane = tid & 63;
    const int l15 = lane & 15, lhi = lane >> 4;
    const int w = tid >> 6, wr = w >> 1, wc = w & 1;
    const int m0 = blockIdx.y * 128, n0 = blockIdx.x * 128;
    const int K = DM, N = DM;
    const int lr8 = lane >> 3;
    const int csw = (lane & 7) ^ lr8;

    __shared__ unsigned short sA[128 * 64];
    __shared__ unsigned short sB[128 * 64];

    f32x4 acc[4][4];
#pragma unroll
    for (int i = 0; i < 4; ++i)
#pragma unroll
        for (int j = 0; j < 4; ++j) acc[i][j] = (f32x4){0.f, 0.f, 0.f, 0.f};

    for (int t = 0; t < 16; ++t) {
        const int k0 = t * 64;
#pragma unroll
        for (int i = 0; i < 4; ++i) {
            int g = w * 4 + i;
            int row = g * 8 + lr8;
            gld16(A + (size_t)(m0 + row) * K + k0 + csw * 8, sA + g * 512);
            gld16(B + (size_t)(n0 + row) * K + k0 + csw * 8, sB + g * 512);
        }
        __syncthreads();
#pragma unroll
        for (int kk = 0; kk < 2; ++kk) {
            bfrag a[4], b[4];
#pragma unroll
            for (int f = 0; f < 4; ++f) {
                int ra = wr * 64 + f * 16 + l15;
                a[f] = *reinterpret_cast<const bfrag*>(
                    sA + ra * 64 + (((kk * 4 + lhi) ^ (ra & 7)) << 3));
                int rb = wc * 64 + f * 16 + l15;
                b[f] = *reinterpret_cast<const bfrag*>(
                    sB + rb * 64 + (((kk * 4 + lhi) ^ (rb & 7)) << 3));
            }
#pragma unroll
            for (int fm = 0; fm < 4; ++fm)
#pragma unroll
                for (int fn = 0; fn < 4; ++fn)
                    acc[fm][fn] =
                        __builtin_amdgcn_mfma_f32_16x16x32_bf16(a[fm], b[fn], acc[fm][fn], 0, 0, 0);
        }
        __syncthreads();
    }

#pragma unroll
    for (int fm = 0; fm < 4; ++fm)
#pragma unroll
        for (int fn = 0; fn < 4; ++fn)
#pragma unroll
            for (int r = 0; r < 4; ++r) {
                int grow = m0 + wr * 64 + fm * 16 + (lhi << 2) + r;
                int gcol = n0 + wc * 64 + fn * 16 + l15;
                Out[(size_t)grow * N + gcol] = acc[fm][fn][r];
            }
}

// ================= fused scores + softmax + PV: zero LDS, zero barriers =================
// Single-buffered frags, batched loads, __launch_bounds__(256,3) so VGPR cap ~170:
// the kernel's ~100 live VGPRs fit WITHOUT scratch spills (rounds 7-9 ran at
// VGPR=48 under (256,5) -> every fragment spilled to scratch -> serialized).
__global__ __launch_bounds__(256, 3) void attn_fused(const unsigned short* __restrict__ qh,
                                                     const unsigned short* __restrict__ kh,
                                                     const unsigned short* __restrict__ vT,
                                                     const float* __restrict__ prev,
                                                     float* __restrict__ scores,
                                                     float* __restrict__ attn,
                                                     unsigned short* __restrict__ ctx) {
    const int z = blockIdx.z;         // b*NH + h
    const int m0 = blockIdx.x * 64;   // Q strip base
    const int tid = threadIdx.x;
    const int lane = tid & 63;
    const int w = tid >> 6;
    const int l15 = lane & 15, lhi = lane >> 4;

    const unsigned short* Qz = qh + (size_t)z * S_LEN * DH;
    const unsigned short* Kz = kh + (size_t)z * S_LEN * DH;
    const unsigned short* Vz = vT + (size_t)z * DH * S_LEN;
    const size_t zbase = (size_t)z * S_LEN * S_LEN;
    const float scale = 0.125f;  // 1/sqrt(64)

    const int qrow = w * 16 + l15;    // local q row this lane owns
    const float* prevRow = prev + zbase + (size_t)(m0 + qrow) * S_LEN;
    float* scoresRow = scores + zbase + (size_t)(m0 + qrow) * S_LEN;
    float* attnRow = attn + zbase + (size_t)(m0 + qrow) * S_LEN;
    const int c4 = lhi * 4;           // phase-1 col offset within 16-group
    const int c8 = lhi * 8;           // phase-2 pf-order col offset within 32-group

    // Q fragments: loaded once (8 VGPRs)
    bfrag qf[2];
#pragma unroll
    for (int kk = 0; kk < 2; ++kk)
        qf[kk] = *reinterpret_cast<const bfrag*>(Qz + (size_t)(m0 + qrow) * DH + kk * 32 +
                                                 lhi * 8);

    float m_r = -1e30f, l_r = 0.f;

    // prologue: prev tile 0 (prev is always loaded one body ahead of consume)
    f32x4 pv4[4];
#pragma unroll
    for (int f = 0; f < 4; ++f)
        pv4[f] = __builtin_nontemporal_load(
            reinterpret_cast<const f32x4*>(prevRow + f * 16 + c4));

    // ---------- phase 1: 32 x 64-col tiles, no barriers ----------
    for (int kt = 0; kt < 32; ++kt) {
        const int n0 = kt * 64;
        // batched K fragment loads (8 independent -> MLP; L2/L3-resident)
        bfrag kf[2][4];
#pragma unroll
        for (int kk = 0; kk < 2; ++kk)
#pragma unroll
            for (int f = 0; f < 4; ++f)
                kf[kk][f] = *reinterpret_cast<const bfrag*>(
                    Kz + (size_t)(n0 + f * 16 + l15) * DH + kk * 32 + lhi * 8);

        f32x4 acc[4];
#pragma unroll
        for (int f = 0; f < 4; ++f) acc[f] = (f32x4){0.f, 0.f, 0.f, 0.f};
#pragma unroll
        for (int kk = 0; kk < 2; ++kk)
#pragma unroll
            for (int f = 0; f < 4; ++f)
                acc[f] = __builtin_amdgcn_mfma_f32_16x16x32_bf16(kf[kk][f], qf[kk], acc[f], 0, 0, 0);

        // consume prev(kt); immediately refill prev(kt+1) (flies until next body)
#pragma unroll
        for (int f = 0; f < 4; ++f)
#pragma unroll
            for (int r = 0; r < 4; ++r) acc[f][r] = acc[f][r] * scale + pv4[f][r];
        if (kt < 31) {
            const int n1 = n0 + 64;
#pragma unroll
            for (int f = 0; f < 4; ++f)
                pv4[f] = __builtin_nontemporal_load(
                    reinterpret_cast<const f32x4*>(prevRow + n1 + f * 16 + c4));
        }
#pragma unroll
        for (int f = 0; f < 4; ++f)
            *reinterpret_cast<f32x4*>(scoresRow + n0 + f * 16 + c4) = acc[f];

        // online softmax (row q spread over lanes l15, l15^16, l15^32, l15^48)
        float pm = acc[0][0];
#pragma unroll
        for (int f = 0; f < 4; ++f)
#pragma unroll
            for (int r = 0; r < 4; ++r) pm = fmaxf(pm, acc[f][r]);
        pm = fmaxf(pm, __shfl_xor(pm, 16));
        pm = fmaxf(pm, __shfl_xor(pm, 32));
        float mnew = fmaxf(m_r, pm);
        float psum = 0.f;
#pragma unroll
        for (int f = 0; f < 4; ++f)
#pragma unroll
            for (int r = 0; r < 4; ++r) psum += __expf(acc[f][r] - mnew);
        psum += __shfl_xor(psum, 16);
        psum += __shfl_xor(psum, 32);
        l_r = l_r * __expf(m_r - mnew) + psum;
        m_r = mnew;
    }

    const float inv_l = 1.0f / l_r;

    // ---------- phase 2: reverse order (hottest scores first), no barriers ----------
    f32x4 acco[4];
#pragma unroll
    for (int f = 0; f < 4; ++f) acco[f] = (f32x4){0.f, 0.f, 0.f, 0.f};

    // prologue: scores tile 31 in pf-order (cols kk*32 + c8 + h*4)
    f32x4 sv[2][2];
#pragma unroll
    for (int kk = 0; kk < 2; ++kk)
#pragma unroll
        for (int h = 0; h < 2; ++h)
            sv[kk][h] = *reinterpret_cast<const f32x4*>(scoresRow + 31 * 64 + kk * 32 + c8 + h * 4);

    for (int kt = 31; kt >= 0; --kt) {
        const int n0 = kt * 64;
        // batched V fragment loads (8 independent, L2/L3); exp chain below hides them
        bfrag vf[2][4];
#pragma unroll
        for (int kk = 0; kk < 2; ++kk)
#pragma unroll
            for (int f = 0; f < 4; ++f)
                vf[kk][f] = *reinterpret_cast<const bfrag*>(
                    Vz + (size_t)(f * 16 + l15) * S_LEN + n0 + kk * 32 + lhi * 8);

        // p = exp(s-m)/l; write attn (NT); pack pf lane-locally (pf-order)
        bfrag pf[2];
#pragma unroll
        for (int kk = 0; kk < 2; ++kk) {
#pragma unroll
            for (int h = 0; h < 2; ++h) {
                f32x4 p4;
#pragma unroll
                for (int r = 0; r < 4; ++r) p4[r] = __expf(sv[kk][h][r] - m_r) * inv_l;
                __builtin_nontemporal_store(
                    p4, reinterpret_cast<f32x4*>(attnRow + n0 + kk * 32 + c8 + h * 4));
#pragma unroll
                for (int r = 0; r < 4; ++r) pf[kk][h * 4 + r] = (short)f2bf(p4[r]);
            }
        }
        // refill sv for next tile (consumed next body)
        if (kt > 0) {
            const int n1 = n0 - 64;
#pragma unroll
            for (int kk = 0; kk < 2; ++kk)
#pragma unroll
                for (int h = 0; h < 2; ++h)
                    sv[kk][h] =
                        *reinterpret_cast<const f32x4*>(scoresRow + n1 + kk * 32 + c8 + h * 4);
        }
#pragma unroll
        for (int kk = 0; kk < 2; ++kk)
#pragma unroll
            for (int f = 0; f < 4; ++f)
                acco[f] = __builtin_amdgcn_mfma_f32_16x16x32_bf16(vf[kk][f], pf[kk], acco[f], 0, 0, 0);
    }

    // write ctx (b, s, h*DH + d) bf16; lane owns q-row, d = f*16 + lhi*4 + r
    const int b = z >> 4, h = z & 15;
    const int s = m0 + qrow;
#pragma unroll
    for (int f = 0; f < 4; ++f) {
        int d0 = f * 16 + c4;
        ushort4 o;
        o.x = f2bf(acco[f][0]); o.y = f2bf(acco[f][1]);
        o.z = f2bf(acco[f][2]); o.w = f2bf(acco[f][3]);
        *reinterpret_cast<ushort4*>(ctx + ((size_t)(b * S_LEN + s)) * DM + h * DH + d0) = o;
    }
}

extern "C" void kernel_launch(void* const* d_in, const int* in_sizes, int n_in, void* d_out,
                              int out_size, void* d_ws, size_t ws_size, hipStream_t stream) {
    const float* Q = (const float*)d_in[0];
    const float* K = (const float*)d_in[1];
    const float* V = (const float*)d_in[2];
    const float* prev = (const float*)d_in[3];
    const float* Wq = (const float*)d_in[4];
    const float* Wk = (const float*)d_in[5];
    const float* Wv = (const float*)d_in[6];
    const float* Wo = (const float*)d_in[7];

    float* out = (float*)d_out;
    float* attn = out + (size_t)BS * DM;
    float* scores = attn + (size_t)NB * NH * S_LEN * S_LEN;

    unsigned short* ws = (unsigned short*)d_ws;
    unsigned short* Qc = ws;
    unsigned short* Kc = Qc + (size_t)BS * DM;
    unsigned short* Vc = Kc + (size_t)BS * DM;
    unsigned short* Wqc = Vc + (size_t)BS * DM;
    unsigned short* Wkc = Wqc + (size_t)DM * DM;
    unsigned short* Wvc = Wkc + (size_t)DM * DM;
    unsigned short* Woc = Wvc + (size_t)DM * DM;
    unsigned short* qh = Woc + (size_t)DM * DM;    // (b,h,s,d) bf16
    unsigned short* kh = qh + (size_t)BS * DM;     // (b,h,s,d) bf16
    unsigned short* vT = kh + (size_t)BS * DM;     // (b,h,d,s) bf16
    unsigned short* ctx = vT + (size_t)BS * DM;    // (b,s,h*d) bf16

    // all casts in one launch
    cast_all<<<16384, 256, 0, stream>>>(Q, K, V, Wq, Wk, Wv, Wo,
                                        Qc, Kc, Vc, Wqc, Wkc, Wvc, Woc);

    // combined QKV projections (768 blocks)
    dim3 gq(DM / 128, BS / 128, 3);
    gemm_qkv<<<gq, 256, 0, stream>>>(Qc, Kc, Vc, Wqc, Wkc, Wvc, qh, kh, vT);

    // fused scores + softmax + PV (1024 blocks, LDS-free, barrier-free, spill-free)
    dim3 ga(S_LEN / 64, 1, NB * NH);
    attn_fused<<<ga, 256, 0, stream>>>(qh, kh, vT, prev, scores, attn, ctx);

    // output projection (256 blocks)
    dim3 gp(DM / 128, BS / 128, 1);
    gemm_out<<<gp, 256, 0, stream>>>(ctx, Woc, out);
}